// Round 7
// baseline (654.131 us; speedup 1.0000x reference)
//
#include <hip/hip_runtime.h>
#include <hip/hip_bf16.h>

// Problem constants
#define S 128
#define BATCH 8192
#define E 300
#define KPAD 640            // 2E=600 padded to multiple of 64
#define H1 2048
#define H2 2048
#define CLS 1221
#define CPAD 1280           // padded N for last GEMM
#define PADTOK 1
#define VOCAB 100000

typedef __bf16 bf16x8 __attribute__((ext_vector_type(8)));
typedef float f32x4 __attribute__((ext_vector_type(4)));

__device__ __forceinline__ float b2f(ushort u) {
  union { unsigned int i; float f; } v; v.i = ((unsigned int)u) << 16; return v.f;
}
__device__ __forceinline__ ushort f2b(float f) {
  unsigned int i = __float_as_uint(f);
  unsigned int r = (i + 0x7FFFu + ((i >> 16) & 1u)) >> 16;
  return (ushort)r;
}
__device__ __forceinline__ void async16(const void* g, void* l) {
  __builtin_amdgcn_global_load_lds(
      (__attribute__((address_space(1))) void*)(void*)(const_cast<void*>(g)),
      (__attribute__((address_space(3))) void*)l, 16, 0, 0);
}

// ---------------------------------------------------------------------------
// Fused preprocessing: emb->bf16, W1->bf16 pad, W2->bf16, Wout->bf16 pad,
// x transpose. One quad (4 elements) per thread.
#define NQ_EMB (VOCAB * E / 4)          // 7,500,000
#define NQ_W1  (H1 * KPAD / 4)          // 327,680
#define NQ_W2  (H1 * H2 / 4)            // 1,048,576
#define NQ_WO  (CPAD * H2 / 4)          // 655,360
#define NQ_XT  (S * BATCH / 4)          // 262,144
#define NQ_TOT (NQ_EMB + NQ_W1 + NQ_W2 + NQ_WO + NQ_XT)

__global__ __launch_bounds__(256) void cvt_all(const float* __restrict__ Ein,
                                               ushort* __restrict__ Eb,
                                               const float* __restrict__ W1,
                                               ushort* __restrict__ W1p,
                                               const float* __restrict__ W2,
                                               ushort* __restrict__ W2b,
                                               const float* __restrict__ Wout,
                                               ushort* __restrict__ Woutp,
                                               const int* __restrict__ x,
                                               int* __restrict__ xT) {
  int q = blockIdx.x * 256 + threadIdx.x;
  if (q < NQ_EMB) {
    float4 v = ((const float4*)Ein)[q];
    ushort4 o;
    o.x = f2b(v.x); o.y = f2b(v.y); o.z = f2b(v.z); o.w = f2b(v.w);
    ((ushort4*)Eb)[q] = o;
    return;
  }
  q -= NQ_EMB;
  if (q < NQ_W1) {
    int row = q / 160;                 // 640/4 quads per padded row
    int k0 = (q - row * 160) * 4;
    ushort4 o; o.x = 0; o.y = 0; o.z = 0; o.w = 0;
    if (k0 < 2 * E) {
      float4 v = *(const float4*)(W1 + (size_t)row * (2 * E) + k0);
      o.x = f2b(v.x); o.y = f2b(v.y); o.z = f2b(v.z); o.w = f2b(v.w);
    }
    ((ushort4*)W1p)[q] = o;
    return;
  }
  q -= NQ_W1;
  if (q < NQ_W2) {
    float4 v = ((const float4*)W2)[q];
    ushort4 o;
    o.x = f2b(v.x); o.y = f2b(v.y); o.z = f2b(v.z); o.w = f2b(v.w);
    ((ushort4*)W2b)[q] = o;
    return;
  }
  q -= NQ_W2;
  if (q < NQ_WO) {
    int n = (q * 4) >> 11;             // row in padded [1280, 2048]
    ushort4 o; o.x = 0; o.y = 0; o.z = 0; o.w = 0;
    if (n < CLS) {
      float4 v = ((const float4*)Wout)[q];
      o.x = f2b(v.x); o.y = f2b(v.y); o.z = f2b(v.z); o.w = f2b(v.w);
    }
    ((ushort4*)Woutp)[q] = o;
    return;
  }
  q -= NQ_WO;
  if (q < NQ_XT) {
    int b = q >> 5;                    // 32 quads per sentence (128 tokens)
    int t4 = (q & 31) * 4;
    int4 o;
    o.x = x[(size_t)(t4 + 0) * BATCH + b];
    o.y = x[(size_t)(t4 + 1) * BATCH + b];
    o.z = x[(size_t)(t4 + 2) * BATCH + b];
    o.w = x[(size_t)(t4 + 3) * BATCH + b];
    ((int4*)xT)[q] = o;
  }
}

// ---------------------------------------------------------------------------
// Stage 1: embedding gather + first-token + masked mean -> feat [B, 640] bf16
// One block (128 threads = 2 waves) per sentence; emb is the bf16 copy.
// Gather is random-access-bound (~630 MB logical @ ~3.6 TB/s effective for
// random 600-B rows); MLP analysis shows ~90 KB/CU in flight -> at ceiling.
__global__ __launch_bounds__(128) void embed_kernel(const int* __restrict__ xT,
                                                    const ushort* __restrict__ emb,
                                                    ushort* __restrict__ feat) {
  __shared__ uint offs[S];
  __shared__ unsigned long long masks[2];
  __shared__ __align__(16) float part[76 * 4];   // wave1 partials: 75 chunks x4
  const int b = blockIdx.x;
  const int t = threadIdx.x;

  int tok = xT[b * S + t];             // coalesced
  offs[t] = (uint)tok * 600u;          // byte offset into bf16 emb table
  unsigned long long m = __ballot(tok != PADTOK);
  if ((t & 63) == 0) masks[t >> 6] = m;
  __syncthreads();

  unsigned long long m0 = masks[0], m1 = masks[1];
  int last;
  if (m1)      last = 127 - __clzll(m1);
  else if (m0) last = 63 - __clzll(m0);
  else         last = S - 1;           // all-pad: ref argmax gives last=S-1
  const int n = last + 1;
  const float inv = 1.0f / (float)n;

  const int w = t >> 6;                // wave id: wave0 even tokens, wave1 odd
  const int lane = t & 63;
  const char* base = (const char*)emb;
  const uint off0 = (uint)lane * 8u;   // chunk byte offset within row (0..511)
  const bool tail = (lane < 11);       // chunks 64..74 cover bytes 512..599
  const uint off1 = 512u + (uint)lane * 8u;

  float a0 = 0.f, a1 = 0.f, a2 = 0.f, a3 = 0.f;   // chunk `lane`
  float c0 = 0.f, c1 = 0.f, c2 = 0.f, c3 = 0.f;   // chunk 64+lane (tail lanes)

  int s = w;
  // main loop: 8 tokens per wave per iteration (16-token span)
  for (; s + 14 < n; s += 16) {
    uint o[8];
#pragma unroll
    for (int j = 0; j < 8; j++) o[j] = offs[s + 2 * j];
    ushort4 u[8];
#pragma unroll
    for (int j = 0; j < 8; j++) u[j] = *(const ushort4*)(base + (o[j] + off0));
    ushort4 v[8];
    if (tail) {
#pragma unroll
      for (int j = 0; j < 8; j++) v[j] = *(const ushort4*)(base + (o[j] + off1));
    }
#pragma unroll
    for (int j = 0; j < 8; j++) {
      a0 += b2f(u[j].x); a1 += b2f(u[j].y);
      a2 += b2f(u[j].z); a3 += b2f(u[j].w);
    }
    if (tail) {
#pragma unroll
      for (int j = 0; j < 8; j++) {
        c0 += b2f(v[j].x); c1 += b2f(v[j].y);
        c2 += b2f(v[j].z); c3 += b2f(v[j].w);
      }
    }
  }
  for (; s < n; s += 2) {
    uint o = offs[s];
    ushort4 u = *(const ushort4*)(base + (o + off0));
    a0 += b2f(u.x); a1 += b2f(u.y); a2 += b2f(u.z); a3 += b2f(u.w);
    if (tail) {
      ushort4 v = *(const ushort4*)(base + (o + off1));
      c0 += b2f(v.x); c1 += b2f(v.y); c2 += b2f(v.z); c3 += b2f(v.w);
    }
  }

  // cross-wave combine: wave1 publishes partials, wave0 reduces + stores mean
  if (w == 1) {
    float4 av; av.x = a0; av.y = a1; av.z = a2; av.w = a3;
    *(float4*)&part[lane * 4] = av;
    if (tail) {
      float4 cv; cv.x = c0; cv.y = c1; cv.z = c2; cv.w = c3;
      *(float4*)&part[(64 + lane) * 4] = cv;
    }
  }
  __syncthreads();

  ushort* fr = feat + (size_t)b * KPAD;
  if (w == 0) {
    float4 pv = *(const float4*)&part[lane * 4];
    ushort4 mo;
    mo.x = f2b((a0 + pv.x) * inv); mo.y = f2b((a1 + pv.y) * inv);
    mo.z = f2b((a2 + pv.z) * inv); mo.w = f2b((a3 + pv.w) * inv);
    *(ushort4*)(fr + E + lane * 4) = mo;           // byte 600+8*lane, aligned
    if (tail) {
      float4 qv = *(const float4*)&part[(64 + lane) * 4];
      ushort4 mo2;
      mo2.x = f2b((c0 + qv.x) * inv); mo2.y = f2b((c1 + qv.y) * inv);
      mo2.z = f2b((c2 + qv.z) * inv); mo2.w = f2b((c3 + qv.w) * inv);
      *(ushort4*)(fr + E + (64 + lane) * 4) = mo2;
    }
  }

  // first-token half: direct bf16 copy (75 threads x 8 B = 600 B)
  const uint o0 = offs[0];
  if (t < 75) {
    *(ushort4*)(fr + 4 * t) = *(const ushort4*)(base + (o0 + 8u * (uint)t));
  } else if (t < 85) {
    // zero the K padding 600..639 (10 threads x 4 elems)
    ushort4 z; z.x = 0; z.y = 0; z.z = 0; z.w = 0;
    *(ushort4*)(fr + 2 * E + 4 * (t - 75)) = z;
  }
}

// ---------------------------------------------------------------------------
// GEMM: identical to R6 (verified passing). 256x256 tile, BK=32, 512 thr,
// 4-slot LDS, staging distance 3, counted vmcnt(8), register prefetch one
// MFMA-cluster ahead, T1 XCD swizzle, T5 setprio.
//
// R7 IS A MEASUREMENT ROUND: each GEMM layer is launched TWICE with
// identical arguments (sequential stream -> duplicate deterministically
// rewrites the same values; no race, no accuracy change, no extra ws).
// total_R7 - total_R6 = L1+L2+L3 duration (cache-warm) — the number the
// top-5 table has hidden for five rounds. Pre-committed reading:
//   +180..215 us -> GEMMs ~700 TF, schedule problem real, keep attacking.
//   +100..130 us -> GEMMs near-roofline; pivot to overhead/fusion.
#define BM2 256
#define BN2 256
#define BK2 32

// stage one 256x32 slab of operand P into LDS region dst (lane-linear dest).
__device__ __forceinline__ void stage32(const ushort* __restrict__ P,
                                        int ld, int org, ushort* dst,
                                        int kg, int tid, int wave) {
  const int sc = tid & 3;              // stored chunk slot
  const int r0 = tid >> 2;             // row within 128-row j-block
#pragma unroll
  for (int j = 0; j < 2; ++j) {
    const int row = j * 128 + r0;
    const int c2 = sc ^ ((row >> 1) & 3);       // source k-chunk (swizzled)
    async16(P + (size_t)(org + row) * ld + kg + c2 * 8,
            (void*)(dst + j * 4096 + wave * 512));
  }
}

#define RD_B(REG, SBASE)                                                     \
  _Pragma("unroll") for (int nf = 0; nf < 4; ++nf) {                         \
    const int row = wc * 64 + nf * 16 + fr;                                  \
    REG[nf] = *(const bf16x8*)&(SBASE)[row * 32 +                            \
                                       ((fq ^ ((row >> 1) & 3)) * 8)];       \
  }
#define RD_A(REG, SBASE, MH)                                                 \
  _Pragma("unroll") for (int f = 0; f < 4; ++f) {                            \
    const int row = wr * 128 + (MH) * 64 + f * 16 + fr;                      \
    REG[f] = *(const bf16x8*)&(SBASE)[row * 32 +                             \
                                      ((fq ^ ((row >> 1) & 3)) * 8)];        \
  }
#define MF(MH, RB, RA)                                                       \
  __builtin_amdgcn_s_setprio(1);                                             \
  _Pragma("unroll") for (int f = 0; f < 4; ++f)                              \
    _Pragma("unroll") for (int nf = 0; nf < 4; ++nf)                         \
      acc[(MH) * 4 + f][nf] = __builtin_amdgcn_mfma_f32_16x16x32_bf16(       \
          RA[f], RB[nf], acc[(MH) * 4 + f][nf], 0, 0, 0);                    \
  __builtin_amdgcn_s_setprio(0);
#define SB0() __builtin_amdgcn_sched_barrier(0)
#define BARS()                                                               \
  __builtin_amdgcn_s_barrier();                                              \
  __builtin_amdgcn_sched_barrier(0);

// steady tile body: reads for t+1 prefetched under t's MFMA clusters.
#define STEADY_BODY(T, RB, RA0, RBN, RA0N)                                   \
  {                                                                          \
    const ushort* sA_c = sm + ((T) & 3) * 16384;                             \
    RD_A(ra1, sA_c, 1);                                                      \
    SB0();                                                                   \
    MF(0, RB, RA0);                                                          \
    BARS();                                                                  \
    {                                                                        \
      ushort* dstS = sm + (((T) + 3) & 3) * 16384;                           \
      stage32(A, lda, m0, dstS, ((T) + 3) * BK2, tid, wave);                 \
      stage32(B, ldb, n0, dstS + 8192, ((T) + 3) * BK2, tid, wave);          \
    }                                                                        \
    asm volatile("s_waitcnt vmcnt(8)" ::: "memory");                         \
    BARS();                                                                  \
    {                                                                        \
      const ushort* sA_n = sm + (((T) + 1) & 3) * 16384;                     \
      RD_B(RBN, sA_n + 8192);                                                \
      RD_A(RA0N, sA_n, 0);                                                   \
    }                                                                        \
    SB0();                                                                   \
    MF(1, RB, ra1);                                                          \
  }

template <bool RELU, bool NGUARD, bool FP32OUT>
__global__ __launch_bounds__(512, 2) void gemm_bt(const ushort* __restrict__ A,
                                                  const ushort* __restrict__ B,
                                                  const float* __restrict__ bias,
                                                  void* __restrict__ Cv,
                                                  int K, int lda, int ldb,
                                                  int ldc, int Nreal) {
  __shared__ __align__(16) ushort sm[65536];    // 128 KB: 4 slots x 32 KB

  const int tid = threadIdx.x;
  const int wave = tid >> 6;
  const int lane = tid & 63;

  // T1: XCD-aware bijective block swizzle (nwg % 8 == 0 for all layers).
  const int gx = gridDim.x;
  const int nwg = gx * gridDim.y;
  const int lin = blockIdx.y * gx + blockIdx.x;
  const int wsw = (lin & 7) * (nwg >> 3) + (lin >> 3);
  const int m0 = (wsw / gx) * BM2;
  const int n0 = (wsw % gx) * BN2;

  const int wr = wave >> 2;            // 0..1 : row half of tile
  const int wc = wave & 3;             // 0..3 : 64-col slice
  const int fr = lane & 15;            // fragment row
  const int fq = lane >> 4;            // k-chunk within slab (0..3)

  f32x4 acc[8][4];
#pragma unroll
  for (int i = 0; i < 8; ++i)
#pragma unroll
    for (int j = 0; j < 4; ++j)
#pragma unroll
      for (int r = 0; r < 4; ++r) acc[i][j][r] = 0.f;

  bf16x8 rbE[4], ra0E[4], rbO[4], ra0O[4], ra1[4];
  const int NT = K / BK2;              // even, >= 4 (20 / 64 / 64)

  // prologue: stage tiles 0,1,2 (12 loads); drain tile0; read its B/A0.
  {
    stage32(A, lda, m0, sm,                 0, tid, wave);
    stage32(B, ldb, n0, sm + 8192,          0, tid, wave);
    stage32(A, lda, m0, sm + 16384,        32, tid, wave);
    stage32(B, ldb, n0, sm + 16384 + 8192, 32, tid, wave);
    stage32(A, lda, m0, sm + 32768,        64, tid, wave);
    stage32(B, ldb, n0, sm + 32768 + 8192, 64, tid, wave);
    asm volatile("s_waitcnt vmcnt(8)" ::: "memory");   // tile0 landed
    BARS();
    RD_B(rbE, sm + 8192);
    RD_A(ra0E, sm, 0);
  }

  // steady: tiles 0 .. NT-4 (odd count since NT even); unroll by 2 + single.
  int t = 0;
  for (; t + 1 <= NT - 4; t += 2) {
    STEADY_BODY(t,     rbE, ra0E, rbO, ra0O);
    STEADY_BODY(t + 1, rbO, ra0O, rbE, ra0E);
  }
  STEADY_BODY(t, rbE, ra0E, rbO, ra0O);   // t == NT-4 (even)

  // tail tile NT-3 (odd parity): no staging; vm(4) drains tile NT-2.
  {
    const ushort* sA_c = sm + ((NT - 3) & 3) * 16384;
    RD_A(ra1, sA_c, 1);
    SB0();
    MF(0, rbO, ra0O);
    BARS();
    asm volatile("s_waitcnt vmcnt(4)" ::: "memory");
    BARS();
    const ushort* sA_n = sm + ((NT - 2) & 3) * 16384;
    RD_B(rbE, sA_n + 8192);
    RD_A(ra0E, sA_n, 0);
    SB0();
    MF(1, rbO, ra1);
  }
  // tail tile NT-2 (even parity): vm(0) drains tile NT-1.
  {
    const ushort* sA_c = sm + ((NT - 2) & 3) * 16384;
    RD_A(ra1, sA_c, 1);
    SB0();
    MF(0, rbE, ra0E);
    BARS();
    asm volatile("s_waitcnt vmcnt(0)" ::: "memory");
    BARS();
    const ushort* sA_n = sm + ((NT - 1) & 3) * 16384;
    RD_B(rbO, sA_n + 8192);
    RD_A(ra0O, sA_n, 0);
    SB0();
    MF(1, rbE, ra1);
  }
  // tail tile NT-1 (odd parity): final two clusters.
  {
    const ushort* sA_c = sm + ((NT - 1) & 3) * 16384;
    RD_A(ra1, sA_c, 1);
    SB0();
    MF(0, rbO, ra0O);
    MF(1, rbO, ra1);
  }

  // Epilogue. 16x16 C/D layout: col = lane&15, row = (lane>>4)*4 + reg.
  // acc[g][nf]: row block = wr*128 + (g>>2)*64 + (g&3)*16.
#pragma unroll
  for (int nf = 0; nf < 4; ++nf) {
    const int col = n0 + wc * 64 + nf * 16 + fr;
    const bool ok = (!NGUARD) || (col < Nreal);
    const float bv = ok ? bias[col] : 0.f;
#pragma unroll
    for (int g = 0; g < 8; ++g) {
      const int rbase = m0 + wr * 128 + (g >> 2) * 64 + (g & 3) * 16 + fq * 4;
#pragma unroll
      for (int rr = 0; rr < 4; ++rr) {
        const int row = rbase + rr;
        float v = acc[g][nf][rr] + bv;
        if (RELU) v = fmaxf(v, 0.f);
        if (ok) {
          if (FP32OUT) ((float*)Cv)[(size_t)row * ldc + col] = v;
          else         ((ushort*)Cv)[(size_t)row * ldc + col] = f2b(v);
        }
      }
    }
  }
}

// ---------------------------------------------------------------------------
extern "C" void kernel_launch(void* const* d_in, const int* in_sizes, int n_in,
                              void* d_out, int out_size, void* d_ws, size_t ws_size,
                              hipStream_t stream) {
  const int* x = (const int*)d_in[0];
  const float* emb = (const float*)d_in[1];
  const float* W1 = (const float*)d_in[2];
  const float* b1 = (const float*)d_in[3];
  const float* W2 = (const float*)d_in[4];
  const float* b2 = (const float*)d_in[5];
  const float* Wout = (const float*)d_in[6];
  const float* bout = (const float*)d_in[7];
  float* out = (float*)d_out;

  char* ws = (char*)d_ws;
  ushort* feat = (ushort*)ws;  ws += (size_t)BATCH * KPAD * 2;   // 10.5 MB
  ushort* h1 = (ushort*)ws;    ws += (size_t)BATCH * H1 * 2;     // 33.6 MB
  ushort* h2 = (ushort*)ws;    ws += (size_t)BATCH * H2 * 2;     // 33.6 MB
  ushort* W1p = (ushort*)ws;   ws += (size_t)H1 * KPAD * 2;      // 2.6 MB
  ushort* W2b = (ushort*)ws;   ws += (size_t)H2 * H1 * 2;        // 8.4 MB
  ushort* Woutp = (ushort*)ws; ws += (size_t)CPAD * H2 * 2;      // 5.2 MB
  ushort* Eb = (ushort*)ws;    ws += (size_t)VOCAB * E * 2;      // 60 MB
  int* xT = (int*)ws;          ws += (size_t)S * BATCH * 4;      // 4 MB

  cvt_all<<<(NQ_TOT + 255) / 256, 256, 0, stream>>>(emb, Eb, W1, W1p, W2, W2b,
                                                    Wout, Woutp, x, xT);
  embed_kernel<<<BATCH, S, 0, stream>>>(xT, Eb, feat);

  // === MEASUREMENT: each GEMM launched twice with identical args. ===
  // Sequential stream -> duplicate rewrites identical values (safe).
  // total_R7 - total_R6 = (L1+L2+L3) warm duration.

  // L1: feat[8192,640] x W1p[2048,640]^T -> relu -> h1[8192,2048] bf16
  gemm_bt<true, false, false><<<dim3(H1 / BN2, BATCH / BM2), 512, 0, stream>>>(
      feat, W1p, b1, (void*)h1, KPAD, KPAD, KPAD, H1, H1);
  gemm_bt<true, false, false><<<dim3(H1 / BN2, BATCH / BM2), 512, 0, stream>>>(
      feat, W1p, b1, (void*)h1, KPAD, KPAD, KPAD, H1, H1);
  // L2: h1 x W2b[2048,2048]^T -> relu -> h2 bf16
  gemm_bt<true, false, false><<<dim3(H2 / BN2, BATCH / BM2), 512, 0, stream>>>(
      h1, W2b, b2, (void*)h2, H1, H1, H1, H2, H2);
  gemm_bt<true, false, false><<<dim3(H2 / BN2, BATCH / BM2), 512, 0, stream>>>(
      h1, W2b, b2, (void*)h2, H1, H1, H1, H2, H2);
  // L3: h2 x Woutp[1280,2048]^T + bias -> out[8192,1221] fp32 (guarded)
  gemm_bt<false, true, true><<<dim3(CPAD / BN2, BATCH / BM2), 512, 0, stream>>>(
      h2, Woutp, bout, (void*)out, H2, H2, H2, CLS, CLS);
  gemm_bt<false, true, true><<<dim3(CPAD / BN2, BATCH / BM2), 512, 0, stream>>>(
      h2, Woutp, bout, (void*)out, H2, H2, H2, CLS, CLS);
}